// Round 1
// baseline (190.794 us; speedup 1.0000x reference)
//
#include <hip/hip_runtime.h>
#include <math.h>

#define T_LEN 2097152
#define K 8
#define D 4
#define NTH 131072          // total threads in main kernel
#define CHUNK (T_LEN / NTH) // 16 time steps per thread
#define TPB 256
#define NBLK (NTH / TPB)    // 512 blocks

// ws layout (as float*):
// [0..63]    Tr (row-stochastic transition probs)
// [64..71]   a[k]   (emission const, pre-scaled by log2e)
// [72..103]  b[k][d] (mu*ivar, pre-scaled by log2e)
// [104..135] c[k][d] (-0.5*ivar, pre-scaled by log2e)
// [136..143] alpha0[k] = pi[k]*exp(em0[k])
// [256 .. 256+NBLK*64)  per-block transfer matrices
// ints at float offset 256+NBLK*64: NBLK shifts

__device__ __forceinline__ float max8(const float v[K]) {
    float a = fmaxf(v[0], v[1]), b = fmaxf(v[2], v[3]);
    float c = fmaxf(v[4], v[5]), d = fmaxf(v[6], v[7]);
    return fmaxf(fmaxf(a, b), fmaxf(c, d));
}

__device__ __forceinline__ void mat_combine(const float L[K][K], const float R[K][K], float C[K][K]) {
#pragma unroll
    for (int i = 0; i < K; ++i) {
        float q[K];
#pragma unroll
        for (int j = 0; j < K; ++j) q[j] = L[i][0] * R[0][j];
#pragma unroll
        for (int k = 1; k < K; ++k)
#pragma unroll
            for (int j = 0; j < K; ++j) q[j] = fmaf(L[i][k], R[k][j], q[j]);
#pragma unroll
        for (int j = 0; j < K; ++j) C[i][j] = q[j];
    }
}

__device__ __forceinline__ void mat_copy(float Dst[K][K], const float S[K][K]) {
#pragma unroll
    for (int i = 0; i < K; ++i)
#pragma unroll
        for (int j = 0; j < K; ++j) Dst[i][j] = S[i][j];
}

// renormalize so max entry is in [1,2) via exact power-of-two scale;
// maintains invariant: true = P * 2^shift
__device__ __forceinline__ void renorm_mat(float P[K][K], int& shift) {
    float mx = 0.f;
#pragma unroll
    for (int i = 0; i < K; ++i)
#pragma unroll
        for (int j = 0; j < K; ++j) mx = fmaxf(mx, P[i][j]);
    int ex = (__float_as_int(mx) >> 23) & 255;
    float scale = __int_as_float((254 - ex) << 23); // 2^(127-ex)
    shift += ex - 127;
#pragma unroll
    for (int i = 0; i < K; ++i)
#pragma unroll
        for (int j = 0; j < K; ++j) P[i][j] *= scale;
}

__global__ void hmm_setup(const float* __restrict__ x,
                          const float* __restrict__ ut,
                          const float* __restrict__ up,
                          const float* __restrict__ mn,
                          const float* __restrict__ lsd,
                          float* __restrict__ ws) {
    if (threadIdx.x != 0 || blockIdx.x != 0) return;
    // transition softmax rows -> probabilities
    for (int i = 0; i < K; ++i) {
        float m = ut[i * K];
        for (int j = 1; j < K; ++j) m = fmaxf(m, ut[i * K + j]);
        float e[K]; float s = 0.f;
        for (int j = 0; j < K; ++j) { e[j] = expf(ut[i * K + j] - m); s += e[j]; }
        float inv = 1.f / s;
        for (int j = 0; j < K; ++j) ws[i * K + j] = e[j] * inv;
    }
    // pi softmax
    float pi[K];
    {
        float m = up[0];
        for (int j = 1; j < K; ++j) m = fmaxf(m, up[j]);
        float s = 0.f;
        for (int j = 0; j < K; ++j) { pi[j] = expf(up[j] - m); s += pi[j]; }
        float inv = 1.f / s;
        for (int j = 0; j < K; ++j) pi[j] *= inv;
    }
    const float L2PI = 1.83787706640934548356f;
    const float LOG2E = 1.44269504088896340736f;
    float an[K], bn[K * D], cn[K * D];
    for (int k = 0; k < K; ++k) {
        float a = 0.f;
        for (int d = 0; d < D; ++d) {
            float lv = lsd[k * D + d];
            float iv = expf(-2.f * lv);
            float mu = mn[k * D + d];
            bn[k * D + d] = mu * iv;
            cn[k * D + d] = -0.5f * iv;
            a += -0.5f * L2PI - lv - 0.5f * mu * mu * iv;
        }
        an[k] = a;
    }
    // alpha0 = pi * exp(em(t=0))  (natural-log coefs)
    for (int k = 0; k < K; ++k) {
        float em = an[k];
        for (int d = 0; d < D; ++d) {
            float xv = x[d];
            em += (cn[k * D + d] * xv + bn[k * D + d]) * xv;
        }
        ws[136 + k] = pi[k] * expf(em);
    }
    // store log2-scaled emission coefs for main loop (e = exp2(em2 + carry))
    for (int k = 0; k < K; ++k) {
        ws[64 + k] = an[k] * LOG2E;
        for (int d = 0; d < D; ++d) {
            ws[72 + k * D + d] = bn[k * D + d] * LOG2E;
            ws[104 + k * D + d] = cn[k * D + d] * LOG2E;
        }
    }
}

__global__ __launch_bounds__(TPB) void hmm_main(const float* __restrict__ x,
                                                const float* __restrict__ cst,
                                                float* __restrict__ bp,
                                                int* __restrict__ bs) {
    __shared__ float lm[128 * 64];
    __shared__ int lsh[128];
    const int tid = blockIdx.x * TPB + threadIdx.x;

    // uniform constants (addresses are thread-independent -> scalar loads)
    float Tr[K][K];
#pragma unroll
    for (int i = 0; i < K; ++i)
#pragma unroll
        for (int j = 0; j < K; ++j) Tr[i][j] = cst[i * K + j];
    float ca[K], cb[K][D], cc[K][D];
#pragma unroll
    for (int k = 0; k < K; ++k) {
        ca[k] = cst[64 + k];
#pragma unroll
        for (int d = 0; d < D; ++d) {
            cb[k][d] = cst[72 + k * D + d];
            cc[k][d] = cst[104 + k * D + d];
        }
    }

    const float4* xv = reinterpret_cast<const float4*>(x) + (size_t)tid * CHUNK;

    float P[K][K];
    int shift = 0;
    if (tid == 0) {
        // chunk 0 starts with diag(alpha0) covering t=0 (no transition before t=0)
#pragma unroll
        for (int i = 0; i < K; ++i)
#pragma unroll
            for (int j = 0; j < K; ++j) P[i][j] = (i == j) ? cst[136 + i] : 0.0f;
    } else {
        float4 x0 = xv[0];
        float e[K];
#pragma unroll
        for (int j = 0; j < K; ++j) {
            float em = ca[j];
            em = fmaf(fmaf(cc[j][0], x0.x, cb[j][0]), x0.x, em);
            em = fmaf(fmaf(cc[j][1], x0.y, cb[j][1]), x0.y, em);
            em = fmaf(fmaf(cc[j][2], x0.z, cb[j][2]), x0.z, em);
            em = fmaf(fmaf(cc[j][3], x0.w, cb[j][3]), x0.w, em);
            e[j] = exp2f(em);
        }
#pragma unroll
        for (int i = 0; i < K; ++i)
#pragma unroll
            for (int j = 0; j < K; ++j) P[i][j] = Tr[i][j] * e[j];
    }

    // time loop: P <- P * (Tr ∘col e_t), power-of-2 renorm folded into next e
    float fcarry = 0.0f;
    int icarry = 0;
    float4 xnext = xv[1];
#pragma unroll 1
    for (int t = 1; t < CHUNK; ++t) {
        float4 xt = xnext;
        int tn = (t + 1 < CHUNK) ? (t + 1) : t; // clamp: avoid OOB prefetch on last iter
        xnext = xv[tn];
        float e[K];
#pragma unroll
        for (int j = 0; j < K; ++j) {
            float em = ca[j];
            em = fmaf(fmaf(cc[j][0], xt.x, cb[j][0]), xt.x, em);
            em = fmaf(fmaf(cc[j][1], xt.y, cb[j][1]), xt.y, em);
            em = fmaf(fmaf(cc[j][2], xt.z, cb[j][2]), xt.z, em);
            em = fmaf(fmaf(cc[j][3], xt.w, cb[j][3]), xt.w, em);
            e[j] = exp2f(em + fcarry);
        }
        shift -= icarry; // carry consumed by this step's e
        float rmx[K];
#pragma unroll
        for (int i = 0; i < K; ++i) {
            float q[K];
#pragma unroll
            for (int j = 0; j < K; ++j) q[j] = P[i][0] * Tr[0][j];
#pragma unroll
            for (int k = 1; k < K; ++k)
#pragma unroll
                for (int j = 0; j < K; ++j) q[j] = fmaf(P[i][k], Tr[k][j], q[j]);
#pragma unroll
            for (int j = 0; j < K; ++j) P[i][j] = q[j] * e[j];
            rmx[i] = max8(P[i]);
        }
        float mx = max8(rmx);
        int ex = (__float_as_int(mx) >> 23) & 255;
        icarry = 127 - ex;
        fcarry = (float)icarry;
    }
    renorm_mat(P, shift); // flush un-consumed carry exactly

    // in-block tree combine over 256 time-ordered chunks (8 levels via LDS)
    const int t = threadIdx.x;
#pragma unroll 1
    for (int lvl = 1; lvl <= 8; ++lvl) {
        const int span = 1 << (lvl - 1);
        bool holder = ((t & (span - 1)) == (span - 1));
        bool sender = holder && (((t >> (lvl - 1)) & 1) == 0);
        bool receiver = holder && (((t >> (lvl - 1)) & 1) == 1);
        int slot = t >> lvl;
        if (sender) {
#pragma unroll
            for (int i = 0; i < K; ++i)
#pragma unroll
                for (int j = 0; j < K; ++j) lm[slot * 64 + i * 8 + j] = P[i][j];
            lsh[slot] = shift;
        }
        __syncthreads();
        if (receiver) {
            float L[K][K];
#pragma unroll
            for (int i = 0; i < K; ++i)
#pragma unroll
                for (int k = 0; k < K; ++k) L[i][k] = lm[slot * 64 + i * 8 + k];
            float C[K][K];
            mat_combine(L, P, C); // L is earlier in time
            mat_copy(P, C);
            shift += lsh[slot];
            renorm_mat(P, shift);
        }
        __syncthreads();
    }
    if (t == TPB - 1) {
        float* o = bp + (size_t)blockIdx.x * 64;
#pragma unroll
        for (int i = 0; i < K; ++i)
#pragma unroll
            for (int j = 0; j < K; ++j) o[i * 8 + j] = P[i][j];
        bs[blockIdx.x] = shift;
    }
}

__global__ void hmm_final(const float* __restrict__ bp,
                          const int* __restrict__ bs,
                          float* __restrict__ out) {
    const int lane = threadIdx.x; // single wave of 64
    const int per = NBLK / 64;    // 8 block-matrices per lane
    const int base = lane * per;

    float P[K][K];
    int shift;
#pragma unroll
    for (int i = 0; i < K; ++i)
#pragma unroll
        for (int j = 0; j < K; ++j) P[i][j] = bp[(size_t)base * 64 + i * 8 + j];
    shift = bs[base];
#pragma unroll 1
    for (int m = 1; m < per; ++m) {
        float R[K][K];
#pragma unroll
        for (int i = 0; i < K; ++i)
#pragma unroll
            for (int j = 0; j < K; ++j) R[i][j] = bp[(size_t)(base + m) * 64 + i * 8 + j];
        float C[K][K];
        mat_combine(P, R, C); // accumulated (earlier) x next
        mat_copy(P, C);
        shift += bs[base + m];
        renorm_mat(P, shift);
    }
    // 6-level shuffle tree across the wave (lane order == time order)
#pragma unroll 1
    for (int d = 1; d < 64; d <<= 1) {
        int os = __shfl_xor(shift, d);
        float O[K][K];
#pragma unroll
        for (int i = 0; i < K; ++i)
#pragma unroll
            for (int j = 0; j < K; ++j) O[i][j] = __shfl_xor(P[i][j], d);
        bool isLeft = ((lane & d) == 0);
        float L[K][K], R[K][K];
#pragma unroll
        for (int i = 0; i < K; ++i)
#pragma unroll
            for (int j = 0; j < K; ++j) {
                L[i][j] = isLeft ? P[i][j] : O[i][j];
                R[i][j] = isLeft ? O[i][j] : P[i][j];
            }
        float C[K][K];
        mat_combine(L, R, C);
        mat_copy(P, C);
        shift += os;
        renorm_mat(P, shift);
    }
    if (lane == 0) {
        float s = 0.f;
#pragma unroll
        for (int i = 0; i < K; ++i)
#pragma unroll
            for (int j = 0; j < K; ++j) s += P[i][j];
        double res = log((double)s) + (double)shift * 0.69314718055994530942;
        out[0] = (float)res;
    }
}

extern "C" void kernel_launch(void* const* d_in, const int* in_sizes, int n_in,
                              void* d_out, int out_size, void* d_ws, size_t ws_size,
                              hipStream_t stream) {
    (void)in_sizes; (void)n_in; (void)out_size; (void)ws_size;
    const float* x  = (const float*)d_in[0];
    const float* ut = (const float*)d_in[1];
    const float* up = (const float*)d_in[2];
    const float* mn = (const float*)d_in[3];
    const float* ls = (const float*)d_in[4];
    float* ws = (float*)d_ws;
    float* out = (float*)d_out;
    float* bp = ws + 256;
    int* bs = (int*)(ws + 256 + (size_t)NBLK * 64);

    hmm_setup<<<1, 64, 0, stream>>>(x, ut, up, mn, ls, ws);
    hmm_main<<<NBLK, TPB, 0, stream>>>(x, ws, bp, bs);
    hmm_final<<<1, 64, 0, stream>>>(bp, bs, out);
}